// Round 1
// 93.693 us; speedup vs baseline: 1.0913x; 1.0913x over previous
//
#include <hip/hip_runtime.h>

// ---------------------------------------------------------------------------
// KAN conv layer: out[b,o,i,j] = sum_{c,p} silu(patch)*bw[o,c,p]
//                              + sum_{c,p,g} Bspline_g(patch)*sw[o,c,p,g]*sc[o,c,p]
// B=16 CIN=32 COUT=64 H=W=64 K=3 -> Ho=Wo=62, P=9, G+k=8 bases
// Implicit GEMM. Spline K=2304 fp8; silu K=288 bf16.
// R8 (103.6us): fp8 spline, dbuf LDS stages, matrix-pipe-bound (~310cyc/step
//     /SIMD vs ~80 LDS).
// R9 (102.3us): spline -> 2x MX-scaled K=128 supersteps + 1 fp8 K=32 step;
//     merged k_spline+k_silu into k_feat.
// R10: (a) sparse de Boor in feature kernel: cubic B-spline has exactly 4
//     nonzero bases; local recursion with uniform knots (denoms 0.4j const)
//     is ~50 VALU ops/elem vs ~230 for the dense 11->8 pyramid. The 4 fp8
//     bytes land via one variable u64 shift (slot i0-3..i0, clamped to 0..7
//     by the shift itself). (b) k_wpack fused into the same dispatch as
//     extra blocks (disjoint ws regions) -> one fewer graph node.
//     k_gemm unchanged.
// ---------------------------------------------------------------------------

typedef short v8s __attribute__((ext_vector_type(8)));
typedef float v4f __attribute__((ext_vector_type(4)));
typedef int   v4i __attribute__((ext_vector_type(4)));
typedef int   v8i __attribute__((ext_vector_type(8)));

#define FSPL8_OFF   0u             // 16*32*64*64*8 = 16,777,216
#define FSILU_OFF   16777472u      // + 4,194,304 -> 20,971,776
#define WMX_OFF     20972032u      // 8*2*4*2*64*16 = 131,072 (MX spline w)
#define WF8_OFF     21103104u      // 8*4*64*8 = 16,384 (leftover fp8 w)
#define WPACKS_OFF  21119488u      // 9*4*64*16 = 36,864 (bf16 silu w)

#define SCALE1 0x7F7F7F7Fu         // E8M0 127 = 1.0 in every byte

__device__ __forceinline__ unsigned short f2bf(float f) {
  unsigned int u = __float_as_uint(f);
  u += 0x7fffu + ((u >> 16) & 1u);          // round-to-nearest-even
  return (unsigned short)(u >> 16);
}

// ---- kernel 1: fused prep: features (blocks 0..1023) + weight pack --------
__global__ __launch_bounds__(256) void k_prep(const float* __restrict__ x,
                                              const float* __restrict__ bw,
                                              const float* __restrict__ sw,
                                              const float* __restrict__ sc,
                                              unsigned char* __restrict__ ws) {
  const int bid = blockIdx.x;
  if (bid >= 1024) {                       // ---- weight-pack blocks ----
    int tid = (bid - 1024) * 256 + threadIdx.x;
    if (tid >= 165888) return;
    if (tid < 147456) {                    // spline fp8: MX region + WF8 region
      int k, dst;
      if (tid < 131072) {                  // WMX [p][ss][ot][pc][lane][16]
        int bh = tid & 15, lane = (tid >> 4) & 63, pc = (tid >> 10) & 1;
        int ss = (tid >> 13) & 1, p = tid >> 14;
        k = p * 288 + ss * 128 + (lane >> 4) * 32 + pc * 16 + bh;
        dst = WMX_OFF + tid;
      } else {                             // WF8 [p][ot][lane][8]
        int t2 = tid - 131072;
        int e = t2 & 7, lane = (t2 >> 3) & 63, p = t2 >> 11;
        k = p * 288 + 256 + (lane >> 4) * 8 + e;
        dst = WF8_OFF + t2;
      }
      int ot = (tid < 131072) ? ((tid >> 11) & 3) : (((tid - 131072) >> 9) & 3);
      int lane = (tid < 131072) ? ((tid >> 4) & 63) : (((tid - 131072) >> 3) & 63);
      int o = (ot << 4) + (lane & 15);
      int chunk = k / 24, u = k - chunk * 24;
      int dj = u >> 3, g = u & 7;
      int c = chunk / 3, di = chunk - c * 3;
      int p_tap = di * 3 + dj;
      float val = sw[((size_t)(o * 32 + c) * 9 + p_tap) * 8 + g] *
                  sc[(size_t)(o * 32 + c) * 9 + p_tap];
      ws[dst] = (unsigned char)(__builtin_amdgcn_cvt_pk_fp8_f32(val, 0.f, 0, false) & 0xff);
    } else {                               // silu bf16: [sp9][ot4][lane64][e8]
      int t2 = tid - 147456;
      int e = t2 & 7, lane = (t2 >> 3) & 63, ot = (t2 >> 9) & 3, sp = t2 >> 11;
      int o = (ot << 4) + (lane & 15);
      int cc = ((lane >> 4) << 3) + e;
      float val = bw[(size_t)(o * 32 + cc) * 9 + sp];
      *(unsigned short*)(ws + WPACKS_OFF + (size_t)t2 * 2) = f2bf(val);
    }
    return;
  }
  // ---- feature blocks: bid = b*64 + y ----
  const int b = bid >> 6, y = bid & 63;
  const int t = threadIdx.x;
  const int xx = t & 63, cg = t >> 6;      // cg: 8-channel group 0..3
  unsigned short h[8];
#pragma unroll
  for (int k = 0; k < 8; ++k) {
    const int c = cg * 8 + k;
    const float v = x[(((size_t)(b * 32 + c) * 64 + y) * 64) + xx];
    h[k] = f2bf(v / (1.0f + __expf(-v)));  // silu
    // sparse cubic B-spline: knots t_i = -2.2 + 0.4*i, i = 0..11.
    // Only bases i0-3..i0 are nonzero; local de Boor, denominators 0.4*j.
    float s = (v + 2.2f) * 2.5f;
    int i0 = (int)floorf(s);
    i0 = i0 < 0 ? 0 : (i0 > 10 ? 10 : i0);
    const float u = (v + 2.2f) - 0.4f * (float)i0;   // in [0, 0.4)
    // j = 1
    float N0 = (0.4f - u) * 2.5f;
    float N1 = u * 2.5f;
    // j = 2
    float a0 = N0 * 1.25f, a1 = N1 * 1.25f;
    N0 = (0.4f - u) * a0;
    float N2 = u * a1;
    N1 = (u + 0.4f) * a0 + (0.8f - u) * a1;
    // j = 3
    float b0 = N0 * (1.0f / 1.2f), b1 = N1 * (1.0f / 1.2f), b2 = N2 * (1.0f / 1.2f);
    N0 = (0.4f - u) * b0;
    float N3 = u * b2;
    N1 = (u + 0.8f) * b0 + (0.8f - u) * b1;
    N2 = (u + 0.4f) * b1 + (1.2f - u) * b2;
    // pack N0..N3 into bytes (i0-3..i0) of a u64; bytes outside 0..7 drop off
    unsigned w0 = __builtin_amdgcn_cvt_pk_fp8_f32(N0, N1, 0, false);
    w0 = __builtin_amdgcn_cvt_pk_fp8_f32(N2, N3, w0, true);
    unsigned long long wd = w0;
    const int sh = i0 * 8 - 24;            // in [-24, 56]
    wd = (sh >= 0) ? (wd << sh) : (wd >> (-sh));
    if (!(v >= -2.2f && v < 2.2f)) wd = 0; // outside grid: all bases zero
    uint2 o;
    o.x = (unsigned)wd;
    o.y = (unsigned)(wd >> 32);
    *(uint2*)(ws + FSPL8_OFF + ((((size_t)(b * 32 + c) * 64 + y) * 64) + xx) * 8) = o;
  }
  uint4 sv;
  sv.x = (unsigned)h[0] | ((unsigned)h[1] << 16);
  sv.y = (unsigned)h[2] | ((unsigned)h[3] << 16);
  sv.z = (unsigned)h[4] | ((unsigned)h[5] << 16);
  sv.w = (unsigned)h[6] | ((unsigned)h[7] << 16);
  *(uint4*)(ws + FSILU_OFF + (size_t)(b * 4096 + y * 64 + xx) * 64 + cg * 16) = sv;
}

// ---- async 16B global -> LDS (lds dest = wave-uniform base + lane*16) ------
__device__ __forceinline__ void ld16(unsigned char* ldsp, const unsigned char* gp) {
  __builtin_amdgcn_global_load_lds(
      (const __attribute__((address_space(1))) unsigned int*)gp,
      (__attribute__((address_space(3))) unsigned int*)ldsp, 16, 0, 0);
}

// ---- kernel 2: implicit GEMM; MX fp8 spline (dbuf) + bf16 silu (pre-staged)-
// Block: 8 waves = (r = w>>1 of 4 rows, oh = w&1 o-half), 256 blocks (1/CU).
// Period p: 2 MX supersteps (K=128) + 1 fp8 K=32 step. wl8 buf = 16 KB WMX[p]
// + 2 KB WF8[p]; fl8 = 4 c-planes x 6 rows x 512 B.
__global__ __launch_bounds__(512) void k_gemm(const unsigned char* __restrict__ ws,
                                              float* __restrict__ out) {
  __shared__ __align__(16) unsigned char wl8[2][18432];
  __shared__ __align__(16) unsigned char fl8[2][12544];
  __shared__ __align__(16) unsigned char wsil[36864];
  __shared__ __align__(16) unsigned char fsil[25088];

  const int blk = blockIdx.x;              // b*16 + ig
  const int b = blk >> 4, ig = blk & 15;
  const int i0 = ig * 4;
  const int tid = threadIdx.x;
  const int wave = tid >> 6, lane = tid & 63;
  const int q = lane >> 4, ln = lane & 15;
  const int r = wave >> 1, oh = wave & 1;
  const int i = i0 + r;

  auto stage_spl = [&](int p, int bi) {    // 30 chunks over 8 waves
#pragma unroll
    for (int it = 0; it < 4; ++it) {
      const int u = wave + it * 8;
      if (u < 16) {
        ld16(&wl8[bi][u * 1024], ws + WMX_OFF + (size_t)p * 16384 + (size_t)u * 1024 + lane * 16);
      } else if (u < 18) {
        ld16(&wl8[bi][u * 1024], ws + WF8_OFF + (size_t)p * 2048 + (size_t)(u - 16) * 1024 + lane * 16);
      } else if (u < 30) {
        const int v = u - 18;
        const int cp = v / 3, cr = v - cp * 3;     // rows {2cr, 2cr+1}
        ld16(&fl8[bi][v * 1024],
             ws + FSPL8_OFF + ((size_t)((b * 32 + p * 4 + cp) * 64 + i0 + cr * 2)) * 512 + lane * 16);
      }
    }
  };

  auto stage_silu = [&]() {                // 60 chunks over 8 waves
#pragma unroll
    for (int it = 0; it < 8; ++it) {
      const int u = wave + it * 8;
      if (u < 36) {
        ld16(&wsil[u * 1024], ws + WPACKS_OFF + (size_t)u * 1024 + lane * 16);
      } else if (u < 60) {
        const int v = u - 36;
        const int rr = v >> 2, p4 = v & 3;
        const int y = min(i0 + rr, 63);
        ld16(&fsil[v * 1024],
             ws + FSILU_OFF + (size_t)(b * 64 + y) * 4096 +
                 (p4 * 16 + (lane >> 2)) * 64 + ((lane & 3) ^ ((lane >> 2) & 3)) * 16);
      }
    }
  };

  // feature run offsets: off(sg, qq) for rid = 4*sg+qq
  auto offf = [&](int sg, int qq) {
    int rid = 4 * sg + qq;
    int ch = rid / 3, sub = rid - ch * 3;
    int cp = ch / 3, di = ch - cp * 3;
    return cp * 3072 + (r + di) * 512 + (sub + ln) * 8;
  };
  int offA[4], offB[4];
#pragma unroll
  for (int qq = 0; qq < 4; ++qq) { offA[qq] = offf(q, qq); offB[qq] = offf(4 + q, qq); }
  const int off8 = offf(8, q);

  v4f acc[2][4];
#pragma unroll
  for (int a = 0; a < 2; ++a)
#pragma unroll
    for (int c = 0; c < 4; ++c) acc[a][c] = (v4f){0.f, 0.f, 0.f, 0.f};

  stage_silu();
  stage_spl(0, 0);
  __syncthreads();

#pragma unroll 1
  for (int t = 0; t < 8; ++t) {
    if (t < 7) stage_spl(t + 1, (t + 1) & 1);
    const unsigned char* wb = wl8[t & 1];
    const unsigned char* fb = fl8[t & 1];
#pragma unroll
    for (int ss = 0; ss < 2; ++ss) {
      union { v8i v; v4i h[2]; } wf[2];
#pragma unroll
      for (int tt = 0; tt < 2; ++tt) {
        const unsigned char* wp = wb + ss * 8192 + (oh * 2 + tt) * 2048 + lane * 16;
        wf[tt].h[0] = *(const v4i*)(wp);
        wf[tt].h[1] = *(const v4i*)(wp + 1024);
      }
      const int* offs = ss ? offB : offA;
      union { v8i v; long l[4]; } ff[4];
#pragma unroll
      for (int pt = 0; pt < 4; ++pt)
#pragma unroll
        for (int qq = 0; qq < 4; ++qq)
          ff[pt].l[qq] = *(const long*)(fb + offs[qq] + pt * 128);
#pragma unroll
      for (int tt = 0; tt < 2; ++tt)
#pragma unroll
        for (int pt = 0; pt < 4; ++pt)
          acc[tt][pt] = __builtin_amdgcn_mfma_scale_f32_16x16x128_f8f6f4(
              wf[tt].v, ff[pt].v, acc[tt][pt], 0, 0, 0, SCALE1, 0, SCALE1);
    }
    {                                      // leftover fp8 K=32 step (sg=8)
      long w8[2], f8[4];
#pragma unroll
      for (int tt = 0; tt < 2; ++tt)
        w8[tt] = *(const long*)(wb + 16384 + (oh * 2 + tt) * 512 + lane * 8);
#pragma unroll
      for (int pt = 0; pt < 4; ++pt)
        f8[pt] = *(const long*)(fb + off8 + pt * 128);
#pragma unroll
      for (int tt = 0; tt < 2; ++tt)
#pragma unroll
        for (int pt = 0; pt < 4; ++pt)
          acc[tt][pt] = __builtin_amdgcn_mfma_f32_16x16x32_fp8_fp8(
              w8[tt], f8[pt], acc[tt][pt], 0, 0, 0);
    }
    __syncthreads();
  }

  // ---- silu phase: bf16, from pre-staged buffers ---------------------------
#pragma unroll
  for (int e = 0; e < 9; ++e) {
    const int di = e / 3, dj = e % 3;
    v8s wb2[2], fb2[4];
#pragma unroll
    for (int tt = 0; tt < 2; ++tt)
      wb2[tt] = *(const v8s*)(&wsil[0] + e * 4096 + (oh * 2 + tt) * 1024 + lane * 16);
    const int xb = dj + ln;
    const int sbase = (r + di) * 4096 + xb * 64 + ((q ^ (xb & 3)) * 16);
#pragma unroll
    for (int pt = 0; pt < 4; ++pt)
      fb2[pt] = *(const v8s*)(&fsil[0] + sbase + pt * 1024);
#pragma unroll
    for (int tt = 0; tt < 2; ++tt)
#pragma unroll
      for (int pt = 0; pt < 4; ++pt)
        acc[tt][pt] = __builtin_amdgcn_mfma_f32_16x16x32_bf16(
            wb2[tt], fb2[pt], acc[tt][pt], 0, 0, 0);
  }

  // ---- epilogue: C/D layout col(n=j)=lane&15, row(m=o)=q*4+reg -------------
  if (i < 62) {
#pragma unroll
    for (int tt = 0; tt < 2; ++tt)
#pragma unroll
      for (int pt = 0; pt < 4; ++pt) {
        const int j = pt * 16 + ln;
        if (j < 62) {
#pragma unroll
          for (int rr = 0; rr < 4; ++rr) {
            const int o = (oh * 2 + tt) * 16 + q * 4 + rr;
            out[(((size_t)b * 64 + o) * 62 + i) * 62 + j] = acc[tt][pt][rr];
          }
        }
      }
  }
}

extern "C" void kernel_launch(void* const* d_in, const int* in_sizes, int n_in,
                              void* d_out, int out_size, void* d_ws, size_t ws_size,
                              hipStream_t stream) {
  const float* x  = (const float*)d_in[0];
  const float* bw = (const float*)d_in[1];
  const float* sw = (const float*)d_in[2];
  const float* sc = (const float*)d_in[3];
  unsigned char* ws = (unsigned char*)d_ws;
  float* out = (float*)d_out;

  hipLaunchKernelGGL(k_prep, dim3(1672), dim3(256), 0, stream, x, bw, sw, sc, ws);
  hipLaunchKernelGGL(k_gemm, dim3(256),  dim3(512), 0, stream, ws, out);
}

// Round 2
// 92.049 us; speedup vs baseline: 1.1108x; 1.0179x over previous
//
#include <hip/hip_runtime.h>

// ---------------------------------------------------------------------------
// KAN conv layer: out[b,o,i,j] = sum_{c,p} silu(patch)*bw[o,c,p]
//                              + sum_{c,p,g} Bspline_g(patch)*sw[o,c,p,g]*sc[o,c,p]
// B=16 CIN=32 COUT=64 H=W=64 K=3 -> Ho=Wo=62, P=9, G+k=8 bases
// Implicit GEMM. Spline K=2304 fp8; silu K=288 bf16.
// R8  (103.6us): fp8 spline, dbuf LDS stages, matrix-pipe-bound.
// R9  (102.3us): spline -> 2x MX-scaled K=128 supersteps + 1 fp8 K=32 step.
// R10 (93.7us):  sparse de Boor (4 nonzero bases, ~50 VALU ops/elem) +
//                wpack fused into feature dispatch.
// R11: features fused INTO k_gemm. Features are pointwise in x, so each
//      block computes its own 4ch x 6row x 64x slab per period (threads
//      0..383, 4 elems each) and ds_writes straight into the fl8/fsil
//      layouts the MFMA loop already reads (byte-identical addressing).
//      feat_load (x global loads) issued BEFORE the MFMA phase, de Boor +
//      ds_write after -> latency hides under MFMA. Kills the 21MB feature
//      write + 25MB re-read and the whole feature dispatch; weight pack
//      remains dispatch 1 (tiny).
// ---------------------------------------------------------------------------

typedef short v8s __attribute__((ext_vector_type(8)));
typedef float v4f __attribute__((ext_vector_type(4)));
typedef int   v4i __attribute__((ext_vector_type(4)));
typedef int   v8i __attribute__((ext_vector_type(8)));

#define WMX_OFF     20972032u      // 8*2*4*2*64*16 = 131,072 (MX spline w)
#define WF8_OFF     21103104u      // 8*4*64*8 = 16,384 (leftover fp8 w)
#define WPACKS_OFF  21119488u      // 9*4*64*16 = 36,864 (bf16 silu w)

#define SCALE1 0x7F7F7F7Fu         // E8M0 127 = 1.0 in every byte

__device__ __forceinline__ unsigned short f2bf(float f) {
  unsigned int u = __float_as_uint(f);
  u += 0x7fffu + ((u >> 16) & 1u);          // round-to-nearest-even
  return (unsigned short)(u >> 16);
}

// ---- kernel 1: pack weights (MX fp8 / leftover fp8 / silu bf16) ------------
__global__ __launch_bounds__(256) void k_wpack(const float* __restrict__ bw,
                                               const float* __restrict__ sw,
                                               const float* __restrict__ sc,
                                               unsigned char* __restrict__ ws) {
  int tid = blockIdx.x * 256 + threadIdx.x;
  if (tid >= 165888) return;
  if (tid < 147456) {                      // spline fp8: MX region + WF8 region
    int k, dst;
    if (tid < 131072) {                    // WMX [p][ss][ot][pc][lane][16]
      int bh = tid & 15, lane = (tid >> 4) & 63, pc = (tid >> 10) & 1;
      int ss = (tid >> 13) & 1, p = tid >> 14;
      k = p * 288 + ss * 128 + (lane >> 4) * 32 + pc * 16 + bh;
      dst = WMX_OFF + tid;
    } else {                               // WF8 [p][ot][lane][8]
      int t2 = tid - 131072;
      int e = t2 & 7, lane = (t2 >> 3) & 63, p = t2 >> 11;
      k = p * 288 + 256 + (lane >> 4) * 8 + e;
      dst = WF8_OFF + t2;
    }
    int ot = (tid < 131072) ? ((tid >> 11) & 3) : (((tid - 131072) >> 9) & 3);
    int lane = (tid < 131072) ? ((tid >> 4) & 63) : (((tid - 131072) >> 3) & 63);
    int o = (ot << 4) + (lane & 15);
    int chunk = k / 24, u = k - chunk * 24;
    int dj = u >> 3, g = u & 7;
    int c = chunk / 3, di = chunk - c * 3;
    int p_tap = di * 3 + dj;
    float val = sw[((size_t)(o * 32 + c) * 9 + p_tap) * 8 + g] *
                sc[(size_t)(o * 32 + c) * 9 + p_tap];
    ws[dst] = (unsigned char)(__builtin_amdgcn_cvt_pk_fp8_f32(val, 0.f, 0, false) & 0xff);
  } else {                                 // silu bf16: [sp9][ot4][lane64][e8]
    int t2 = tid - 147456;
    int e = t2 & 7, lane = (t2 >> 3) & 63, ot = (t2 >> 9) & 3, sp = t2 >> 11;
    int o = (ot << 4) + (lane & 15);
    int cc = ((lane >> 4) << 3) + e;
    float val = bw[(size_t)(o * 32 + cc) * 9 + sp];
    *(unsigned short*)(ws + WPACKS_OFF + (size_t)t2 * 2) = f2bf(val);
  }
}

// ---- async 16B global -> LDS (lds dest = wave-uniform base + lane*16) ------
__device__ __forceinline__ void ld16(unsigned char* ldsp, const unsigned char* gp) {
  __builtin_amdgcn_global_load_lds(
      (const __attribute__((address_space(1))) unsigned int*)gp,
      (__attribute__((address_space(3))) unsigned int*)ldsp, 16, 0, 0);
}

// ---- kernel 2: fused features + implicit GEMM ------------------------------
// Block: 8 waves = (r = w>>1 of 4 rows, oh = w&1 o-half), 256 blocks (1/CU).
// Period p: 2 MX supersteps (K=128) + 1 fp8 K=32 step. wl8 buf = 16 KB WMX[p]
// + 2 KB WF8[p]; fl8 = 4 c-planes x 6 rows x 512 B (computed in-block).
__global__ __launch_bounds__(512) void k_gemm(const unsigned char* __restrict__ ws,
                                              const float* __restrict__ x,
                                              float* __restrict__ out) {
  __shared__ __align__(16) unsigned char wl8[2][18432];
  __shared__ __align__(16) unsigned char fl8[2][12544];
  __shared__ __align__(16) unsigned char wsil[36864];
  __shared__ __align__(16) unsigned char fsil[25088];

  const int blk = blockIdx.x;              // b*16 + ig
  const int b = blk >> 4, ig = blk & 15;
  const int i0 = ig * 4;
  const int tid = threadIdx.x;
  const int wave = tid >> 6, lane = tid & 63;
  const int q = lane >> 4, ln = lane & 15;
  const int r = wave >> 1, oh = wave & 1;
  const int i = i0 + r;

  // feature-compute assignment: threads 0..383 own (row 0..5, x 0..63),
  // all 4 channels of the period.
  const bool factive = tid < 384;
  const int frow = tid >> 6, fx = tid & 63;
  const int fy = min(i0 + frow, 63);       // clamp: rows >=64 only feed j/i>=62 (discarded)

  auto stage_w = [&](int p, int bi) {      // 18 weight chunks over 8 waves
#pragma unroll
    for (int it = 0; it < 3; ++it) {
      const int u = wave + it * 8;
      if (u < 16) {
        ld16(&wl8[bi][u * 1024], ws + WMX_OFF + (size_t)p * 16384 + (size_t)u * 1024 + lane * 16);
      } else if (u < 18) {
        ld16(&wl8[bi][u * 1024], ws + WF8_OFF + (size_t)p * 2048 + (size_t)(u - 16) * 1024 + lane * 16);
      }
    }
  };

  auto stage_wsil = [&]() {                // 36 chunks over 8 waves
#pragma unroll
    for (int it = 0; it < 5; ++it) {
      const int u = wave + it * 8;
      if (u < 36) ld16(&wsil[u * 1024], ws + WPACKS_OFF + (size_t)u * 1024 + lane * 16);
    }
  };

  auto feat_load = [&](int p, float* v) {  // issue x loads (latency hides under MFMA)
    if (factive) {
#pragma unroll
      for (int cp = 0; cp < 4; ++cp)
        v[cp] = x[((size_t)(b * 32 + p * 4 + cp) * 64 + fy) * 64 + fx];
    }
  };

  auto feat_store = [&](int p, int bi, const float* v) {  // de Boor + ds_write
    if (factive) {
      unsigned long long spl[4];
      unsigned short hh[4];
#pragma unroll
      for (int cp = 0; cp < 4; ++cp) {
        const float vv = v[cp];
        hh[cp] = f2bf(vv / (1.0f + __expf(-vv)));        // silu
        // sparse cubic B-spline: knots t_i = -2.2 + 0.4*i; 4 nonzero bases.
        float s = (vv + 2.2f) * 2.5f;
        int ii = (int)floorf(s);
        ii = ii < 0 ? 0 : (ii > 10 ? 10 : ii);
        const float uu = (vv + 2.2f) - 0.4f * (float)ii; // in [0, 0.4)
        float N0 = (0.4f - uu) * 2.5f;
        float N1 = uu * 2.5f;
        float a0 = N0 * 1.25f, a1 = N1 * 1.25f;
        N0 = (0.4f - uu) * a0;
        float N2 = uu * a1;
        N1 = (uu + 0.4f) * a0 + (0.8f - uu) * a1;
        float c0 = N0 * (1.0f / 1.2f), c1 = N1 * (1.0f / 1.2f), c2 = N2 * (1.0f / 1.2f);
        N0 = (0.4f - uu) * c0;
        float N3 = uu * c2;
        N1 = (uu + 0.8f) * c0 + (0.8f - uu) * c1;
        N2 = (uu + 0.4f) * c1 + (1.2f - uu) * c2;
        unsigned w0 = __builtin_amdgcn_cvt_pk_fp8_f32(N0, N1, 0, false);
        w0 = __builtin_amdgcn_cvt_pk_fp8_f32(N2, N3, w0, true);
        unsigned long long wd = w0;
        const int sh = ii * 8 - 24;        // bytes i0-3..i0; out-of-range drops off
        wd = (sh >= 0) ? (wd << sh) : (wd >> (-sh));
        if (!(vv >= -2.2f && vv < 2.2f)) wd = 0;
        spl[cp] = wd;
      }
#pragma unroll
      for (int cp = 0; cp < 4; ++cp)
        *(unsigned long long*)(&fl8[bi][cp * 3072 + frow * 512 + fx * 8]) = spl[cp];
      // silu bf16, swizzled layout matching the silu-phase reads:
      // slot = (cg ^ (x&3)); period p covers c = 4p..4p+3 -> cg = p>>1, half = p&1
      unsigned long long sp = (unsigned long long)((unsigned)hh[0] | ((unsigned)hh[1] << 16)) |
                              ((unsigned long long)((unsigned)hh[2] | ((unsigned)hh[3] << 16)) << 32);
      *(unsigned long long*)(&fsil[frow * 4096 + fx * 64 +
                                   (((p >> 1) ^ (fx & 3)) * 16) + (p & 1) * 8]) = sp;
    }
  };

  // feature run offsets: off(sg, qq) for rid = 4*sg+qq
  auto offf = [&](int sg, int qq) {
    int rid = 4 * sg + qq;
    int ch = rid / 3, sub = rid - ch * 3;
    int cp = ch / 3, di = ch - cp * 3;
    return cp * 3072 + (r + di) * 512 + (sub + ln) * 8;
  };
  int offA[4], offB[4];
#pragma unroll
  for (int qq = 0; qq < 4; ++qq) { offA[qq] = offf(q, qq); offB[qq] = offf(4 + q, qq); }
  const int off8 = offf(8, q);

  v4f acc[2][4];
#pragma unroll
  for (int a = 0; a < 2; ++a)
#pragma unroll
    for (int c = 0; c < 4; ++c) acc[a][c] = (v4f){0.f, 0.f, 0.f, 0.f};

  // prologue: weights async; period-0 features computed in-block
  stage_wsil();
  stage_w(0, 0);
  {
    float v0[4];
    feat_load(0, v0);
    feat_store(0, 0, v0);
  }
  __syncthreads();

#pragma unroll 1
  for (int t = 0; t < 8; ++t) {
    float vbuf[4];
    if (t < 7) {
      stage_w(t + 1, (t + 1) & 1);
      feat_load(t + 1, vbuf);              // issue loads; consumed after MFMA
    }
    const unsigned char* wb = wl8[t & 1];
    const unsigned char* fb = fl8[t & 1];
#pragma unroll
    for (int ss = 0; ss < 2; ++ss) {
      union { v8i v; v4i h[2]; } wf[2];
#pragma unroll
      for (int tt = 0; tt < 2; ++tt) {
        const unsigned char* wp = wb + ss * 8192 + (oh * 2 + tt) * 2048 + lane * 16;
        wf[tt].h[0] = *(const v4i*)(wp);
        wf[tt].h[1] = *(const v4i*)(wp + 1024);
      }
      const int* offs = ss ? offB : offA;
      union { v8i v; long l[4]; } ff[4];
#pragma unroll
      for (int pt = 0; pt < 4; ++pt)
#pragma unroll
        for (int qq = 0; qq < 4; ++qq)
          ff[pt].l[qq] = *(const long*)(fb + offs[qq] + pt * 128);
#pragma unroll
      for (int tt = 0; tt < 2; ++tt)
#pragma unroll
        for (int pt = 0; pt < 4; ++pt)
          acc[tt][pt] = __builtin_amdgcn_mfma_scale_f32_16x16x128_f8f6f4(
              wf[tt].v, ff[pt].v, acc[tt][pt], 0, 0, 0, SCALE1, 0, SCALE1);
    }
    {                                      // leftover fp8 K=32 step (sg=8)
      long w8[2], f8[4];
#pragma unroll
      for (int tt = 0; tt < 2; ++tt)
        w8[tt] = *(const long*)(wb + 16384 + (oh * 2 + tt) * 512 + lane * 8);
#pragma unroll
      for (int pt = 0; pt < 4; ++pt)
        f8[pt] = *(const long*)(fb + off8 + pt * 128);
#pragma unroll
      for (int tt = 0; tt < 2; ++tt)
#pragma unroll
        for (int pt = 0; pt < 4; ++pt)
          acc[tt][pt] = __builtin_amdgcn_mfma_f32_16x16x32_fp8_fp8(
              w8[tt], f8[pt], acc[tt][pt], 0, 0, 0);
    }
    if (t < 7) feat_store(t + 1, (t + 1) & 1, vbuf);
    __syncthreads();
  }

  // ---- silu phase: bf16, from in-block-computed buffers --------------------
#pragma unroll
  for (int e = 0; e < 9; ++e) {
    const int di = e / 3, dj = e % 3;
    v8s wb2[2], fb2[4];
#pragma unroll
    for (int tt = 0; tt < 2; ++tt)
      wb2[tt] = *(const v8s*)(&wsil[0] + e * 4096 + (oh * 2 + tt) * 1024 + lane * 16);
    const int xb = dj + ln;
    const int sbase = (r + di) * 4096 + xb * 64 + ((q ^ (xb & 3)) * 16);
#pragma unroll
    for (int pt = 0; pt < 4; ++pt)
      fb2[pt] = *(const v8s*)(&fsil[0] + sbase + pt * 1024);
#pragma unroll
    for (int tt = 0; tt < 2; ++tt)
#pragma unroll
      for (int pt = 0; pt < 4; ++pt)
        acc[tt][pt] = __builtin_amdgcn_mfma_f32_16x16x32_bf16(
            wb2[tt], fb2[pt], acc[tt][pt], 0, 0, 0);
  }

  // ---- epilogue: C/D layout col(n=j)=lane&15, row(m=o)=q*4+reg -------------
  if (i < 62) {
#pragma unroll
    for (int tt = 0; tt < 2; ++tt)
#pragma unroll
      for (int pt = 0; pt < 4; ++pt) {
        const int j = pt * 16 + ln;
        if (j < 62) {
#pragma unroll
          for (int rr = 0; rr < 4; ++rr) {
            const int o = (oh * 2 + tt) * 16 + q * 4 + rr;
            out[(((size_t)b * 64 + o) * 62 + i) * 62 + j] = acc[tt][pt][rr];
          }
        }
      }
  }
}

extern "C" void kernel_launch(void* const* d_in, const int* in_sizes, int n_in,
                              void* d_out, int out_size, void* d_ws, size_t ws_size,
                              hipStream_t stream) {
  const float* x  = (const float*)d_in[0];
  const float* bw = (const float*)d_in[1];
  const float* sw = (const float*)d_in[2];
  const float* sc = (const float*)d_in[3];
  unsigned char* ws = (unsigned char*)d_ws;
  float* out = (float*)d_out;

  hipLaunchKernelGGL(k_wpack, dim3(648), dim3(256), 0, stream, bw, sw, sc, ws);
  hipLaunchKernelGGL(k_gemm,  dim3(256), dim3(512), 0, stream, ws, x, out);
}

// Round 4
// 91.500 us; speedup vs baseline: 1.1175x; 1.0060x over previous
//
#include <hip/hip_runtime.h>

// ---------------------------------------------------------------------------
// KAN conv layer: out[b,o,i,j] = sum_{c,p} silu(patch)*bw[o,c,p]
//                              + sum_{c,p,g} Bspline_g(patch)*sw[o,c,p,g]*sc[o,c,p]
// B=16 CIN=32 COUT=64 H=W=64 K=3 -> Ho=Wo=62, P=9, G+k=8 bases
// Implicit GEMM. Spline K=2304 fp8; silu K=288 bf16.
// R8  (103.6us): fp8 spline, dbuf LDS stages, matrix-pipe-bound.
// R9  (102.3us): spline -> 2x MX-scaled K=128 supersteps + 1 fp8 K=32 step.
// R10 (93.7us):  sparse de Boor (4 nonzero bases) + wpack fused into feature.
// R11 (92.0us):  features fused INTO k_gemm (feat_load before MFMA,
//                feat_store after -> store was ON the critical path).
// R12 (infra fail, never ran): (a) feature pipeline deepened one period:
//      store(t+1) at loop TOP, load(t+2) issued; post-MFMA tail is just the
//      barrier. (b) k_wpack coalesced: one thread per (o,c,p_tap) reads 32B
//      contiguous sw + 1 sc, writes ONE aligned u64. (c) setprio(1) around
//      MFMA clusters.
// R13: R12 resubmit; vnext zero-init + no stale rotate (close the only UB).
// ---------------------------------------------------------------------------

typedef short v8s __attribute__((ext_vector_type(8)));
typedef float v4f __attribute__((ext_vector_type(4)));
typedef int   v4i __attribute__((ext_vector_type(4)));
typedef int   v8i __attribute__((ext_vector_type(8)));

#define WMX_OFF     20972032u      // 8*2*4*2*64*16 = 131,072 (MX spline w)
#define WF8_OFF     21103104u      // 8*4*64*8 = 16,384 (leftover fp8 w)
#define WPACKS_OFF  21119488u      // 9*4*64*16 = 36,864 (bf16 silu w)

#define SCALE1 0x7F7F7F7Fu         // E8M0 127 = 1.0 in every byte

__device__ __forceinline__ unsigned short f2bf(float f) {
  unsigned int u = __float_as_uint(f);
  u += 0x7fffu + ((u >> 16) & 1u);          // round-to-nearest-even
  return (unsigned short)(u >> 16);
}

// ---- kernel 1: pack weights, read-coalesced --------------------------------
__global__ __launch_bounds__(256) void k_wpack(const float* __restrict__ bw,
                                               const float* __restrict__ sw,
                                               const float* __restrict__ sc,
                                               unsigned char* __restrict__ ws) {
  const int bid = blockIdx.x, t = threadIdx.x;
  if (bid < 72) {                          // spline: thread per (o,c,p_tap)
    const int idx = bid * 256 + t;         // 0..18431 == (o*32+c)*9 + p_tap
    const int o = idx / 288, rem = idx - o * 288;
    const int c = rem / 9, p_tap = rem - c * 9;
    const float scv = sc[idx];
    const float4 v0 = *(const float4*)(sw + (size_t)idx * 8);
    const float4 v1 = *(const float4*)(sw + (size_t)idx * 8 + 4);
    unsigned lo = __builtin_amdgcn_cvt_pk_fp8_f32(v0.x * scv, v0.y * scv, 0, false);
    lo = __builtin_amdgcn_cvt_pk_fp8_f32(v0.z * scv, v0.w * scv, lo, true);
    unsigned hi = __builtin_amdgcn_cvt_pk_fp8_f32(v1.x * scv, v1.y * scv, 0, false);
    hi = __builtin_amdgcn_cvt_pk_fp8_f32(v1.z * scv, v1.w * scv, hi, true);
    const int di = p_tap / 3, dj = p_tap - di * 3;
    const int k0 = 24 * (c * 3 + di) + 8 * dj;       // k0 % 16 in {0,8}
    const int p = k0 / 288, r288 = k0 - p * 288;
    const int ot = o >> 4, ol = o & 15;
    size_t dst;
    if (r288 < 256) {                      // WMX [p][ss][ot][pc][lane][16]
      const int ss = r288 >> 7, r128 = r288 & 127;
      const int lh = r128 >> 5, r32 = r128 & 31;
      const int pc = r32 >> 4, bh = r32 & 15;        // bh in {0,8}
      dst = WMX_OFF + p * 16384 + ss * 8192 + ot * 2048 + pc * 1024 +
            (lh * 16 + ol) * 16 + bh;
    } else {                               // WF8 [p][ot][lane][8]
      const int r2 = r288 - 256;
      dst = WF8_OFF + p * 2048 + ot * 512 + ((r2 >> 3) * 16 + ol) * 8;
    }
    *(unsigned long long*)(ws + dst) =
        (unsigned long long)lo | ((unsigned long long)hi << 32);
  } else {                                 // silu bf16: thread per (o,cc)
    const int idx2 = (bid - 72) * 256 + t;
    if (idx2 >= 2048) return;
    const int o = idx2 >> 5, cc = idx2 & 31;
    const int ot = o >> 4;
    const int lane = ((cc >> 3) << 4) | (o & 15);
    const int e = cc & 7;
#pragma unroll
    for (int sp = 0; sp < 9; ++sp) {
      const float val = bw[(size_t)(o * 32 + cc) * 9 + sp];
      *(unsigned short*)(ws + WPACKS_OFF + sp * 4096 + ot * 1024 + lane * 16 + e * 2) =
          f2bf(val);
    }
  }
}

// ---- async 16B global -> LDS (lds dest = wave-uniform base + lane*16) ------
__device__ __forceinline__ void ld16(unsigned char* ldsp, const unsigned char* gp) {
  __builtin_amdgcn_global_load_lds(
      (const __attribute__((address_space(1))) unsigned int*)gp,
      (__attribute__((address_space(3))) unsigned int*)ldsp, 16, 0, 0);
}

// ---- kernel 2: fused features + implicit GEMM ------------------------------
// Block: 8 waves = (r = w>>1 of 4 rows, oh = w&1 o-half), 256 blocks (1/CU).
// Period p: 2 MX supersteps (K=128) + 1 fp8 K=32 step. wl8 buf = 16 KB WMX[p]
// + 2 KB WF8[p]; fl8 = 4 c-planes x 6 rows x 512 B (computed in-block).
__global__ __launch_bounds__(512) void k_gemm(const unsigned char* __restrict__ ws,
                                              const float* __restrict__ x,
                                              float* __restrict__ out) {
  __shared__ __align__(16) unsigned char wl8[2][18432];
  __shared__ __align__(16) unsigned char fl8[2][12544];
  __shared__ __align__(16) unsigned char wsil[36864];
  __shared__ __align__(16) unsigned char fsil[25088];

  const int blk = blockIdx.x;              // b*16 + ig
  const int b = blk >> 4, ig = blk & 15;
  const int i0 = ig * 4;
  const int tid = threadIdx.x;
  const int wave = tid >> 6, lane = tid & 63;
  const int q = lane >> 4, ln = lane & 15;
  const int r = wave >> 1, oh = wave & 1;
  const int i = i0 + r;

  // feature-compute assignment: threads 0..383 own (row 0..5, x 0..63),
  // all 4 channels of the period.
  const bool factive = tid < 384;
  const int frow = tid >> 6, fx = tid & 63;
  const int fy = min(i0 + frow, 63);       // clamp: rows >=64 only feed i>=62 (discarded)

  auto stage_w = [&](int p, int bi) {      // 18 weight chunks over 8 waves
#pragma unroll
    for (int it = 0; it < 3; ++it) {
      const int u = wave + it * 8;
      if (u < 16) {
        ld16(&wl8[bi][u * 1024], ws + WMX_OFF + (size_t)p * 16384 + (size_t)u * 1024 + lane * 16);
      } else if (u < 18) {
        ld16(&wl8[bi][u * 1024], ws + WF8_OFF + (size_t)p * 2048 + (size_t)(u - 16) * 1024 + lane * 16);
      }
    }
  };

  auto stage_wsil = [&]() {                // 36 chunks over 8 waves
#pragma unroll
    for (int it = 0; it < 5; ++it) {
      const int u = wave + it * 8;
      if (u < 36) ld16(&wsil[u * 1024], ws + WPACKS_OFF + (size_t)u * 1024 + lane * 16);
    }
  };

  auto feat_load = [&](int p, float* v) {  // issue x loads (latency hides under MFMA)
    if (factive) {
#pragma unroll
      for (int cp = 0; cp < 4; ++cp)
        v[cp] = x[((size_t)(b * 32 + p * 4 + cp) * 64 + fy) * 64 + fx];
    }
  };

  auto feat_store = [&](int p, int bi, const float* v) {  // de Boor + ds_write
    if (factive) {
      unsigned long long spl[4];
      unsigned short hh[4];
#pragma unroll
      for (int cp = 0; cp < 4; ++cp) {
        const float vv = v[cp];
        hh[cp] = f2bf(vv / (1.0f + __expf(-vv)));        // silu
        // sparse cubic B-spline: knots t_i = -2.2 + 0.4*i; 4 nonzero bases.
        float s = (vv + 2.2f) * 2.5f;
        int ii = (int)floorf(s);
        ii = ii < 0 ? 0 : (ii > 10 ? 10 : ii);
        const float uu = (vv + 2.2f) - 0.4f * (float)ii; // in [0, 0.4)
        float N0 = (0.4f - uu) * 2.5f;
        float N1 = uu * 2.5f;
        float a0 = N0 * 1.25f, a1 = N1 * 1.25f;
        N0 = (0.4f - uu) * a0;
        float N2 = uu * a1;
        N1 = (uu + 0.4f) * a0 + (0.8f - uu) * a1;
        float c0 = N0 * (1.0f / 1.2f), c1 = N1 * (1.0f / 1.2f), c2 = N2 * (1.0f / 1.2f);
        N0 = (0.4f - uu) * c0;
        float N3 = uu * c2;
        N1 = (uu + 0.8f) * c0 + (0.8f - uu) * c1;
        N2 = (uu + 0.4f) * c1 + (1.2f - uu) * c2;
        unsigned w0 = __builtin_amdgcn_cvt_pk_fp8_f32(N0, N1, 0, false);
        w0 = __builtin_amdgcn_cvt_pk_fp8_f32(N2, N3, w0, true);
        unsigned long long wd = w0;
        const int sh = ii * 8 - 24;        // bytes i0-3..i0; out-of-range drops off
        wd = (sh >= 0) ? (wd << sh) : (wd >> (-sh));
        if (!(vv >= -2.2f && vv < 2.2f)) wd = 0;
        spl[cp] = wd;
      }
#pragma unroll
      for (int cp = 0; cp < 4; ++cp)
        *(unsigned long long*)(&fl8[bi][cp * 3072 + frow * 512 + fx * 8]) = spl[cp];
      // silu bf16, swizzled layout matching the silu-phase reads
      unsigned long long sp = (unsigned long long)((unsigned)hh[0] | ((unsigned)hh[1] << 16)) |
                              ((unsigned long long)((unsigned)hh[2] | ((unsigned)hh[3] << 16)) << 32);
      *(unsigned long long*)(&fsil[frow * 4096 + fx * 64 +
                                   (((p >> 1) ^ (fx & 3)) * 16) + (p & 1) * 8]) = sp;
    }
  };

  // feature run offsets: off(sg, qq) for rid = 4*sg+qq
  auto offf = [&](int sg, int qq) {
    int rid = 4 * sg + qq;
    int ch = rid / 3, sub = rid - ch * 3;
    int cp = ch / 3, di = ch - cp * 3;
    return cp * 3072 + (r + di) * 512 + (sub + ln) * 8;
  };
  int offA[4], offB[4];
#pragma unroll
  for (int qq = 0; qq < 4; ++qq) { offA[qq] = offf(q, qq); offB[qq] = offf(4 + q, qq); }
  const int off8 = offf(8, q);

  v4f acc[2][4];
#pragma unroll
  for (int a = 0; a < 2; ++a)
#pragma unroll
    for (int c = 0; c < 4; ++c) acc[a][c] = (v4f){0.f, 0.f, 0.f, 0.f};

  // prologue: x loads for periods 0,1 first (longest latency), then weight
  // staging, then de Boor for period 0.
  float v0[4], vcur[4];
  float vnext[4] = {0.f, 0.f, 0.f, 0.f};
  feat_load(0, v0);
  feat_load(1, vcur);
  stage_wsil();
  stage_w(0, 0);
  feat_store(0, 0, v0);
  __syncthreads();

#pragma unroll 1
  for (int t = 0; t < 8; ++t) {
    // top-of-loop: finish period t+1 features (writes fl8[(t+1)&1], which no
    // one reads this iteration) and issue period t+2 x loads + t+1 weights.
    if (t < 7) {
      feat_store(t + 1, (t + 1) & 1, vcur);
      stage_w(t + 1, (t + 1) & 1);
    }
    if (t < 6) feat_load(t + 2, vnext);

    const unsigned char* wb = wl8[t & 1];
    const unsigned char* fb = fl8[t & 1];
    __builtin_amdgcn_s_setprio(1);
#pragma unroll
    for (int ss = 0; ss < 2; ++ss) {
      union { v8i v; v4i h[2]; } wf[2];
#pragma unroll
      for (int tt = 0; tt < 2; ++tt) {
        const unsigned char* wp = wb + ss * 8192 + (oh * 2 + tt) * 2048 + lane * 16;
        wf[tt].h[0] = *(const v4i*)(wp);
        wf[tt].h[1] = *(const v4i*)(wp + 1024);
      }
      const int* offs = ss ? offB : offA;
      union { v8i v; long l[4]; } ff[4];
#pragma unroll
      for (int pt = 0; pt < 4; ++pt)
#pragma unroll
        for (int qq = 0; qq < 4; ++qq)
          ff[pt].l[qq] = *(const long*)(fb + offs[qq] + pt * 128);
#pragma unroll
      for (int tt = 0; tt < 2; ++tt)
#pragma unroll
        for (int pt = 0; pt < 4; ++pt)
          acc[tt][pt] = __builtin_amdgcn_mfma_scale_f32_16x16x128_f8f6f4(
              wf[tt].v, ff[pt].v, acc[tt][pt], 0, 0, 0, SCALE1, 0, SCALE1);
    }
    {                                      // leftover fp8 K=32 step (sg=8)
      long w8[2], f8[4];
#pragma unroll
      for (int tt = 0; tt < 2; ++tt)
        w8[tt] = *(const long*)(wb + 16384 + (oh * 2 + tt) * 512 + lane * 8);
#pragma unroll
      for (int pt = 0; pt < 4; ++pt)
        f8[pt] = *(const long*)(fb + off8 + pt * 128);
#pragma unroll
      for (int tt = 0; tt < 2; ++tt)
#pragma unroll
        for (int pt = 0; pt < 4; ++pt)
          acc[tt][pt] = __builtin_amdgcn_mfma_f32_16x16x32_fp8_fp8(
              w8[tt], f8[pt], acc[tt][pt], 0, 0, 0);
    }
    __builtin_amdgcn_s_setprio(0);
    if (t < 6) {
#pragma unroll
      for (int cp = 0; cp < 4; ++cp) vcur[cp] = vnext[cp];
    }
    __syncthreads();
  }

  // ---- silu phase: bf16, from in-block-computed buffers --------------------
#pragma unroll
  for (int e = 0; e < 9; ++e) {
    const int di = e / 3, dj = e % 3;
    v8s wb2[2], fb2[4];
#pragma unroll
    for (int tt = 0; tt < 2; ++tt)
      wb2[tt] = *(const v8s*)(&wsil[0] + e * 4096 + (oh * 2 + tt) * 1024 + lane * 16);
    const int xb = dj + ln;
    const int sbase = (r + di) * 4096 + xb * 64 + ((q ^ (xb & 3)) * 16);
#pragma unroll
    for (int pt = 0; pt < 4; ++pt)
      fb2[pt] = *(const v8s*)(&fsil[0] + sbase + pt * 1024);
    __builtin_amdgcn_s_setprio(1);
#pragma unroll
    for (int tt = 0; tt < 2; ++tt)
#pragma unroll
      for (int pt = 0; pt < 4; ++pt)
        acc[tt][pt] = __builtin_amdgcn_mfma_f32_16x16x32_bf16(
            wb2[tt], fb2[pt], acc[tt][pt], 0, 0, 0);
    __builtin_amdgcn_s_setprio(0);
  }

  // ---- epilogue: C/D layout col(n=j)=lane&15, row(m=o)=q*4+reg -------------
  if (i < 62) {
#pragma unroll
    for (int tt = 0; tt < 2; ++tt)
#pragma unroll
      for (int pt = 0; pt < 4; ++pt) {
        const int j = pt * 16 + ln;
        if (j < 62) {
#pragma unroll
          for (int rr = 0; rr < 4; ++rr) {
            const int o = (oh * 2 + tt) * 16 + q * 4 + rr;
            out[(((size_t)b * 64 + o) * 62 + i) * 62 + j] = acc[tt][pt][rr];
          }
        }
      }
  }
}

extern "C" void kernel_launch(void* const* d_in, const int* in_sizes, int n_in,
                              void* d_out, int out_size, void* d_ws, size_t ws_size,
                              hipStream_t stream) {
  const float* x  = (const float*)d_in[0];
  const float* bw = (const float*)d_in[1];
  const float* sw = (const float*)d_in[2];
  const float* sc = (const float*)d_in[3];
  unsigned char* ws = (unsigned char*)d_ws;
  float* out = (float*)d_out;

  hipLaunchKernelGGL(k_wpack, dim3(80),  dim3(256), 0, stream, bw, sw, sc, ws);
  hipLaunchKernelGGL(k_gemm,  dim3(256), dim3(512), 0, stream, ws, x, out);
}